// Round 1
// baseline (236.463 us; speedup 1.0000x reference)
//
#include <hip/hip_runtime.h>

// EdgeMLP: out[e] = sigmoid( 0.5*dot(relu(af)+relu(ar), W2[:,1]-W2[:,0]) + (b2[1]-b2[0]) )
// with af/ar the fwd/rev first-layer pre-activations. Symmetric/antisymmetric
// decomposition shares the first-layer work between fwd and rev MLPs:
//   P = 0.5*(W1[0:6] + W1[6:12]),  M = 0.5*(W1[0:6] - W1[6:12])
//   c[j] = b1[j] + sum_i (xs+xt)[i]*P[i][j]
//   m[j] =        sum_i (xs-xt)[i]*M[i][j]
//   af[j] = c[j]+m[j]+ea *W1[12][j]
//   ar[j] = c[j]-m[j]+eaT*W1[12][j]

// Packed weight table layout in d_ws (floats):
//   [0,60)    P[i][j]   (i<6, j<10)
//   [60,120)  M[i][j]
//   [120,130) w12[j] = W1[12][j]
//   [130,140) b1[j]
//   [140,150) w2d[j] = 0.5*(W2[j][1]-W2[j][0])
//   [150]     b2d    = b2[1]-b2[0]
//   [151]     pad

__global__ void prep_weights(const float* __restrict__ W1, const float* __restrict__ b1,
                             const float* __restrict__ W2, const float* __restrict__ b2,
                             float* __restrict__ w) {
    int t = threadIdx.x;
    if (t < 60) {
        int i = t / 10, j = t % 10;
        float a = W1[i * 10 + j];
        float c = W1[(i + 6) * 10 + j];
        w[t]      = 0.5f * (a + c);   // P
        w[60 + t] = 0.5f * (a - c);   // M
    }
    if (t < 10) {
        w[120 + t] = W1[120 + t];                          // W1 row 12
        w[130 + t] = b1[t];
        w[140 + t] = 0.5f * (W2[t * 2 + 1] - W2[t * 2]);   // 0.5 folded in
    }
    if (t == 0) {
        w[150] = b2[1] - b2[0];
        w[151] = 0.0f;
    }
}

// 152 weight floats held in VGPRs for the whole grid-stride loop.
// __launch_bounds__(256,2): 2 waves/SIMD -> VGPR cap 256, no spill of the
// ~190-reg working set. 512 blocks = 2 blocks/CU, all co-resident.
__launch_bounds__(256, 2)
__global__ void edge_mlp(const float* __restrict__ x, const int* __restrict__ ei,
                         const float* __restrict__ ea, const float* __restrict__ eaT,
                         const float* __restrict__ wg, float* __restrict__ out, int E) {
    float W[152];
    const float4* w4 = (const float4*)wg;
#pragma unroll
    for (int k = 0; k < 38; ++k) {
        float4 v = w4[k];
        W[4 * k + 0] = v.x; W[4 * k + 1] = v.y;
        W[4 * k + 2] = v.z; W[4 * k + 3] = v.w;
    }

    const float2* xr = (const float2*)x;   // x rows are 24B = 3x float2, 8B-aligned
    int tid = blockIdx.x * blockDim.x + threadIdx.x;
    int stride = gridDim.x * blockDim.x;

    for (int e = tid; e < E; e += stride) {
        int si = ei[e];
        int ti = ei[E + e];
        float fea  = ea[e];
        float feaT = eaT[e];

        float2 a0 = xr[3 * si], a1 = xr[3 * si + 1], a2 = xr[3 * si + 2];
        float2 c0 = xr[3 * ti], c1 = xr[3 * ti + 1], c2 = xr[3 * ti + 2];
        float xs[6] = {a0.x, a0.y, a1.x, a1.y, a2.x, a2.y};
        float xt[6] = {c0.x, c0.y, c1.x, c1.y, c2.x, c2.y};

        float sv[6], dv[6];
#pragma unroll
        for (int i = 0; i < 6; ++i) { sv[i] = xs[i] + xt[i]; dv[i] = xs[i] - xt[i]; }

        float cacc[10], macc[10];
#pragma unroll
        for (int j = 0; j < 10; ++j) { cacc[j] = W[130 + j]; macc[j] = 0.0f; }
#pragma unroll
        for (int i = 0; i < 6; ++i) {
#pragma unroll
            for (int j = 0; j < 10; ++j) {
                cacc[j] = fmaf(sv[i], W[i * 10 + j],      cacc[j]);
                macc[j] = fmaf(dv[i], W[60 + i * 10 + j], macc[j]);
            }
        }

        float z = W[150];
#pragma unroll
        for (int j = 0; j < 10; ++j) {
            float af = fmaf(fea,  W[120 + j], cacc[j] + macc[j]);
            float ar = fmaf(feaT, W[120 + j], cacc[j] - macc[j]);
            float h  = fmaxf(af, 0.0f) + fmaxf(ar, 0.0f);
            z = fmaf(h, W[140 + j], z);
        }

        out[e] = 1.0f / (1.0f + __expf(-z));
    }
}

extern "C" void kernel_launch(void* const* d_in, const int* in_sizes, int n_in,
                              void* d_out, int out_size, void* d_ws, size_t ws_size,
                              hipStream_t stream) {
    const float* x   = (const float*)d_in[0];
    const int*   ei  = (const int*)d_in[1];
    const float* ea  = (const float*)d_in[2];
    const float* eaT = (const float*)d_in[3];
    const float* W1  = (const float*)d_in[4];
    const float* b1  = (const float*)d_in[5];
    const float* W2  = (const float*)d_in[6];
    const float* b2  = (const float*)d_in[7];
    float* out = (float*)d_out;
    float* w   = (float*)d_ws;
    int E = in_sizes[2];   // edge_attr element count = N_EDGES

    prep_weights<<<1, 64, 0, stream>>>(W1, b1, W2, b2, w);
    edge_mlp<<<512, 256, 0, stream>>>(x, ei, ea, eaT, w, out, E);
}

// Round 2
// 233.038 us; speedup vs baseline: 1.0147x; 1.0147x over previous
//
#include <hip/hip_runtime.h>

// EdgeMLP: out[e] = sigmoid( 0.5*dot(relu(af)+relu(ar), W2[:,1]-W2[:,0]) + (b2[1]-b2[0]) )
// Symmetric/antisymmetric decomposition shares first-layer work between the
// fwd and rev MLPs:
//   P = 0.5*(W1[0:6] + W1[6:12]),  M = 0.5*(W1[0:6] - W1[6:12])
//   c[j] = b1[j] + sum_i (xs+xt)[i]*P[i][j]
//   m[j] =        sum_i (xs-xt)[i]*M[i][j]
//   af[j] = c[j]+m[j]+ea *W1[12][j],  ar[j] = c[j]-m[j]+eaT*W1[12][j]
//
// Packed weight table in d_ws (floats):
//   [0,60) P | [60,120) M | [120,130) w12 | [130,140) b1 | [140,150) w2d | [150] b2d

__global__ void prep_weights(const float* __restrict__ W1, const float* __restrict__ b1,
                             const float* __restrict__ W2, const float* __restrict__ b2,
                             float* __restrict__ w) {
    int t = threadIdx.x;
    if (t < 60) {
        int i = t / 10, j = t % 10;
        float a = W1[i * 10 + j];
        float c = W1[(i + 6) * 10 + j];
        w[t]      = 0.5f * (a + c);   // P
        w[60 + t] = 0.5f * (a - c);   // M
    }
    if (t < 10) {
        w[120 + t] = W1[120 + t];                          // W1 row 12
        w[130 + t] = b1[t];
        w[140 + t] = 0.5f * (W2[t * 2 + 1] - W2[t * 2]);   // 0.5 folded in
    }
    if (t == 0) {
        w[150] = b2[1] - b2[0];
        w[151] = 0.0f;
    }
}

// One edge per thread. Weights are wave-uniform -> compiler scalarizes to
// s_load / SGPRs (R1 evidence: VGPR=28, SGPR=112). Occupancy was the R1
// bottleneck (21%, latency-bound on x gathers) -> 8 waves/SIMD now.
__launch_bounds__(256, 8)
__global__ void edge_mlp(const float* __restrict__ x, const int* __restrict__ ei,
                         const float* __restrict__ ea, const float* __restrict__ eaT,
                         const float* __restrict__ wg, float* __restrict__ out, int E) {
    int e = blockIdx.x * 256 + threadIdx.x;
    if (e >= E) return;

    // Streaming inputs: non-temporal so the 100MB streams don't evict the
    // 2.4MB x table (gather working set) from L2.
    int   si   = __builtin_nontemporal_load(ei + e);
    int   ti   = __builtin_nontemporal_load(ei + E + e);
    float fea  = __builtin_nontemporal_load(ea + e);
    float feaT = __builtin_nontemporal_load(eaT + e);

    const float2* xr = (const float2*)x;   // x rows are 24B = 3x float2, 8B-aligned
    float2 a0 = xr[3 * si], a1 = xr[3 * si + 1], a2 = xr[3 * si + 2];
    float2 c0 = xr[3 * ti], c1 = xr[3 * ti + 1], c2 = xr[3 * ti + 2];
    float xs[6] = {a0.x, a0.y, a1.x, a1.y, a2.x, a2.y};
    float xt[6] = {c0.x, c0.y, c1.x, c1.y, c2.x, c2.y};

    float sv[6], dv[6];
#pragma unroll
    for (int i = 0; i < 6; ++i) { sv[i] = xs[i] + xt[i]; dv[i] = xs[i] - xt[i]; }

    float cacc[10], macc[10];
#pragma unroll
    for (int j = 0; j < 10; ++j) { cacc[j] = wg[130 + j]; macc[j] = 0.0f; }
#pragma unroll
    for (int i = 0; i < 6; ++i) {
#pragma unroll
        for (int j = 0; j < 10; ++j) {
            cacc[j] = fmaf(sv[i], wg[i * 10 + j],      cacc[j]);
            macc[j] = fmaf(dv[i], wg[60 + i * 10 + j], macc[j]);
        }
    }

    float z = wg[150];
#pragma unroll
    for (int j = 0; j < 10; ++j) {
        float af = fmaf(fea,  wg[120 + j], cacc[j] + macc[j]);
        float ar = fmaf(feaT, wg[120 + j], cacc[j] - macc[j]);
        float h  = fmaxf(af, 0.0f) + fmaxf(ar, 0.0f);
        z = fmaf(h, wg[140 + j], z);
    }

    float r = 1.0f / (1.0f + __expf(-z));
    __builtin_nontemporal_store(r, out + e);
}

extern "C" void kernel_launch(void* const* d_in, const int* in_sizes, int n_in,
                              void* d_out, int out_size, void* d_ws, size_t ws_size,
                              hipStream_t stream) {
    const float* x   = (const float*)d_in[0];
    const int*   ei  = (const int*)d_in[1];
    const float* ea  = (const float*)d_in[2];
    const float* eaT = (const float*)d_in[3];
    const float* W1  = (const float*)d_in[4];
    const float* b1  = (const float*)d_in[5];
    const float* W2  = (const float*)d_in[6];
    const float* b2  = (const float*)d_in[7];
    float* out = (float*)d_out;
    float* w   = (float*)d_ws;
    int E = in_sizes[2];   // edge_attr element count = N_EDGES

    prep_weights<<<1, 64, 0, stream>>>(W1, b1, W2, b2, w);
    int blocks = (E + 255) / 256;
    edge_mlp<<<blocks, 256, 0, stream>>>(x, ei, ea, eaT, w, out, E);
}

// Round 3
// 195.420 us; speedup vs baseline: 1.2100x; 1.1925x over previous
//
#include <hip/hip_runtime.h>
#include <hip/hip_fp16.h>

// EdgeMLP: out[e] = sigmoid( 0.5*dot(relu(af)+relu(ar), W2[:,1]-W2[:,0]) + (b2[1]-b2[0]) )
// Symmetric/antisymmetric decomposition shares first-layer work:
//   P = 0.5*(W1[0:6]+W1[6:12]), M = 0.5*(W1[0:6]-W1[6:12])
//   cacc = b1 + P^T(xs+xt); macc = M^T(xs-xt)
//   af = cacc+macc+ea*w12, ar = cacc-macc+eaT*w12
//
// R2 post-mortem: kernel is L2 gather-request-rate bound (6 divergent 8B
// requests/edge ≈ 16 req/cyc/XCD ≈ 125us — matches). Fix: pack x rows into
// 16B fp16 rows so each endpoint is ONE dwordx4 request (2/edge).
//
// d_ws layout: [0,152) weight floats | byte 4096: packed x, 16B/node.

__global__ void prep(const float* __restrict__ W1, const float* __restrict__ b1,
                     const float* __restrict__ W2, const float* __restrict__ b2,
                     const float* __restrict__ x, float* __restrict__ ws, int N) {
    int t = blockIdx.x * 256 + threadIdx.x;
    if (t < N) {   // pack x row t -> 6 fp16 + 2 pad (16B, aligned)
        const float2* xr = (const float2*)x;
        float2 a0 = xr[3 * t], a1 = xr[3 * t + 1], a2 = xr[3 * t + 2];
        union { __half2 h[4]; float4 f; } pk;
        pk.h[0] = __floats2half2_rn(a0.x, a0.y);
        pk.h[1] = __floats2half2_rn(a1.x, a1.y);
        pk.h[2] = __floats2half2_rn(a2.x, a2.y);
        pk.h[3] = __floats2half2_rn(0.0f, 0.0f);
        ((float4*)((char*)ws + 4096))[t] = pk.f;
    }
    if (blockIdx.x == 0) {
        int u = threadIdx.x;
        if (u < 60) {
            int i = u / 10, j = u % 10;
            float a = W1[i * 10 + j];
            float c = W1[(i + 6) * 10 + j];
            ws[u]      = 0.5f * (a + c);   // P
            ws[60 + u] = 0.5f * (a - c);   // M
        }
        if (u < 10) {
            ws[120 + u] = W1[120 + u];                          // W1 row 12
            ws[130 + u] = b1[u];
            ws[140 + u] = 0.5f * (W2[u * 2 + 1] - W2[u * 2]);   // 0.5 folded
        }
        if (u == 0) ws[150] = b2[1] - b2[0];
    }
}

// One edge per thread; weights scalarize to SGPRs (R1: VGPR=28/SGPR=112).
__launch_bounds__(256, 8)
__global__ void edge_mlp(const float4* __restrict__ xp, const int* __restrict__ ei,
                         const float* __restrict__ ea, const float* __restrict__ eaT,
                         const float* __restrict__ wg, float* __restrict__ out, int E) {
    int e = blockIdx.x * 256 + threadIdx.x;
    if (e >= E) return;

    int   si   = __builtin_nontemporal_load(ei + e);
    int   ti   = __builtin_nontemporal_load(ei + E + e);
    float fea  = __builtin_nontemporal_load(ea + e);
    float feaT = __builtin_nontemporal_load(eaT + e);

    float4 rs = xp[si];   // single 16B gather per endpoint
    float4 rt = xp[ti];
    const __half2* hs = (const __half2*)&rs;
    const __half2* ht = (const __half2*)&rt;

    float sv[6], dv[6];
#pragma unroll
    for (int k = 0; k < 3; ++k) {
        float2 fs = __half22float2(hs[k]);
        float2 ft = __half22float2(ht[k]);
        sv[2 * k]     = fs.x + ft.x;  dv[2 * k]     = fs.x - ft.x;
        sv[2 * k + 1] = fs.y + ft.y;  dv[2 * k + 1] = fs.y - ft.y;
    }

    float cacc[10], macc[10];
#pragma unroll
    for (int j = 0; j < 10; ++j) { cacc[j] = wg[130 + j]; macc[j] = 0.0f; }
#pragma unroll
    for (int i = 0; i < 6; ++i) {
#pragma unroll
        for (int j = 0; j < 10; ++j) {
            cacc[j] = fmaf(sv[i], wg[i * 10 + j],      cacc[j]);
            macc[j] = fmaf(dv[i], wg[60 + i * 10 + j], macc[j]);
        }
    }

    float z = wg[150];
#pragma unroll
    for (int j = 0; j < 10; ++j) {
        float af = fmaf(fea,  wg[120 + j], cacc[j] + macc[j]);
        float ar = fmaf(feaT, wg[120 + j], cacc[j] - macc[j]);
        float h  = fmaxf(af, 0.0f) + fmaxf(ar, 0.0f);
        z = fmaf(h, wg[140 + j], z);
    }

    float r = 1.0f / (1.0f + __expf(-z));
    __builtin_nontemporal_store(r, out + e);
}

extern "C" void kernel_launch(void* const* d_in, const int* in_sizes, int n_in,
                              void* d_out, int out_size, void* d_ws, size_t ws_size,
                              hipStream_t stream) {
    const float* x   = (const float*)d_in[0];
    const int*   ei  = (const int*)d_in[1];
    const float* ea  = (const float*)d_in[2];
    const float* eaT = (const float*)d_in[3];
    const float* W1  = (const float*)d_in[4];
    const float* b1  = (const float*)d_in[5];
    const float* W2  = (const float*)d_in[6];
    const float* b2  = (const float*)d_in[7];
    float* out = (float*)d_out;
    float* ws  = (float*)d_ws;
    int E = in_sizes[2];          // N_EDGES
    int N = in_sizes[0] / 6;      // N_NODES

    int pblocks = (N + 255) / 256;
    prep<<<pblocks, 256, 0, stream>>>(W1, b1, W2, b2, x, ws, N);

    const float4* xp = (const float4*)((char*)d_ws + 4096);
    int blocks = (E + 255) / 256;
    edge_mlp<<<blocks, 256, 0, stream>>>(xp, ei, ea, eaT, ws, out, E);
}